// Round 1
// baseline (16.102 us; speedup 1.0000x reference)
//
#include <hip/hip_runtime.h>

#define KK 17
#define MM 30
#define BB 8
#define HWN 262144

// One block, 256 threads. Threads [32b, 32b+31] handle batch b.
// Lane (tid&31) < 30 owns person m = lane: does the 17 gathers, mean, pull.
// Then the 32 lanes of each group split the 30x30 push pairs.
// Deterministic: fixed reduction order, no atomics, d_out fully overwritten.
__global__ __launch_bounds__(256) void ae_loss_kernel(
    const float* __restrict__ tags,       // (B, K, HW) f32
    const int*   __restrict__ kp,         // (B, M, K, 2) i32: [idx, vis]
    float*       __restrict__ out)        // out[0]=pull_total, out[1]=push_total
{
    const int tid  = threadIdx.x;
    const int b    = tid >> 5;   // 0..7
    const int lane = tid & 31;   // 0..31

    __shared__ float s_mean[BB][MM];
    __shared__ int   s_valid[BB][MM];
    __shared__ float s_res[BB][2];   // [pull_loss, push_loss] per batch

    float pull_pp = 0.0f;

    if (lane < MM) {
        const int m = lane;
        float g[KK];
        unsigned int maskbits = 0u;
        float sum = 0.0f;
        int cnt = 0;
        const int base = ((b * MM + m) * KK) * 2;
        #pragma unroll
        for (int k = 0; k < KK; ++k) {
            const int idx = kp[base + 2 * k + 0];
            const int vis = kp[base + 2 * k + 1];
            float val = 0.0f;
            if (vis > 0) {
                val = tags[(size_t)(b * KK + k) * HWN + idx];
                maskbits |= (1u << k);
                cnt += 1;
            }
            g[k] = val;
            sum += val;
        }
        const float safe_cnt = (float)(cnt > 1 ? cnt : 1);
        const float mean = sum / safe_cnt;
        float pp = 0.0f;
        #pragma unroll
        for (int k = 0; k < KK; ++k) {
            if (maskbits & (1u << k)) {
                const float d = g[k] - mean;
                pp += d * d;
            }
        }
        pp /= safe_cnt;
        const int valid = (cnt > 0) ? 1 : 0;
        pull_pp = valid ? pp : 0.0f;
        s_mean[b][m]  = mean;
        s_valid[b][m] = valid;
    }
    __syncthreads();

    // --- reduce pull across the 32-lane group (xor masks <32 stay in-half) ---
    float pull = pull_pp;
    #pragma unroll
    for (int off = 16; off >= 1; off >>= 1)
        pull += __shfl_xor(pull, off);

    // --- push: distribute the 900 pairs across 32 lanes ---
    float push = 0.0f;
    for (int p = lane; p < MM * MM; p += 32) {
        const int m1 = p / MM;
        const int m2 = p - m1 * MM;
        if (s_valid[b][m1] && s_valid[b][m2]) {
            const float d = s_mean[b][m1] - s_mean[b][m2];
            push += __expf(-d * d);
        }
    }
    #pragma unroll
    for (int off = 16; off >= 1; off >>= 1)
        push += __shfl_xor(push, off);

    // --- per-batch finalize on lane 0 of each group ---
    if (lane == 0) {
        int n = 0;
        #pragma unroll
        for (int m = 0; m < MM; ++m) n += s_valid[b][m];
        const float nf = (float)n;
        float push_loss = 0.0f;
        if (n > 1) {
            float denom = nf * (nf - 1.0f);
            if (denom < 1.0f) denom = 1.0f;
            push_loss = push / denom * 0.5f;
        }
        float pull_loss = 0.0f;
        if (n > 0) {
            float denom = nf > 1.0f ? nf : 1.0f;
            pull_loss = pull / denom;
        }
        s_res[b][0] = pull_loss;
        s_res[b][1] = push_loss;
    }
    __syncthreads();

    if (tid == 0) {
        float pull_total = 0.0f, push_total = 0.0f;
        #pragma unroll
        for (int bb = 0; bb < BB; ++bb) {
            pull_total += s_res[bb][0];
            push_total += s_res[bb][1];
        }
        out[0] = pull_total;   // reference: (pull.sum(), push.sum())
        out[1] = push_total;
    }
}

extern "C" void kernel_launch(void* const* d_in, const int* in_sizes, int n_in,
                              void* d_out, int out_size, void* d_ws, size_t ws_size,
                              hipStream_t stream) {
    const float* tags = (const float*)d_in[0];
    const int*   kp   = (const int*)d_in[1];
    float*       out  = (float*)d_out;
    ae_loss_kernel<<<dim3(1), dim3(256), 0, stream>>>(tags, kp, out);
}

// Round 2
// 14.218 us; speedup vs baseline: 1.1325x; 1.1325x over previous
//
#include <hip/hip_runtime.h>

#define KK 17
#define MM 30
#define BB 8
#define HWN 262144

// One block, 256 threads. Threads [32b, 32b+31] handle batch b.
// Lane (tid&31) < 30 owns person m = lane: 17 branch-free int2 kp loads,
// then 17 branch-free unconditional tag gathers (mask applied as f32 mul),
// matching the reference's unconditional pred[arange(K), idx] gather.
// Then the 32 lanes of each group split the 30x30 push pairs.
// Deterministic: fixed reduction order, no atomics, d_out fully overwritten.
__global__ __launch_bounds__(256) void ae_loss_kernel(
    const float* __restrict__ tags,       // (B, K, HW) f32
    const int*   __restrict__ kp,         // (B, M, K, 2) i32: [idx, vis]
    float*       __restrict__ out)        // out[0]=pull_total, out[1]=push_total
{
    const int tid  = threadIdx.x;
    const int b    = tid >> 5;   // 0..7
    const int lane = tid & 31;   // 0..31

    __shared__ float s_mean[BB][MM];
    __shared__ int   s_valid[BB][MM];
    __shared__ float s_res[BB][2];   // [pull_loss, push_loss] per batch

    float pull_pp = 0.0f;

    if (lane < MM) {
        const int m = lane;
        // kp pairs for this person: 17 contiguous int2 at 8-B-aligned base.
        const int2* __restrict__ kp2 =
            (const int2*)(kp + (size_t)(b * MM + m) * KK * 2);

        int   idxv[KK];
        float msk[KK];
        int   cnt = 0;
        #pragma unroll
        for (int k = 0; k < KK; ++k) {
            const int2 p = kp2[k];          // {idx, vis} — independent loads
            idxv[k] = p.x;
            const int v = (p.y > 0) ? 1 : 0;
            msk[k]  = (float)v;
            cnt    += v;
        }

        // Unconditional gathers (reference gathers regardless of vis).
        float g[KK];
        #pragma unroll
        for (int k = 0; k < KK; ++k)
            g[k] = tags[(size_t)(b * KK + k) * HWN + idxv[k]];

        float sum = 0.0f;
        #pragma unroll
        for (int k = 0; k < KK; ++k)
            sum += g[k] * msk[k];

        const float safe_cnt = (float)(cnt > 1 ? cnt : 1);
        const float mean = sum / safe_cnt;

        float pp = 0.0f;
        #pragma unroll
        for (int k = 0; k < KK; ++k) {
            const float d = g[k] - mean;
            pp += msk[k] * d * d;
        }
        pp /= safe_cnt;

        const int valid = (cnt > 0) ? 1 : 0;
        pull_pp = valid ? pp : 0.0f;
        s_mean[b][m]  = mean;
        s_valid[b][m] = valid;
    }
    __syncthreads();

    // --- reduce pull across the 32-lane group (xor offsets <32 stay in-group) ---
    float pull = pull_pp;
    #pragma unroll
    for (int off = 16; off >= 1; off >>= 1)
        pull += __shfl_xor(pull, off);

    // --- push: distribute the 900 pairs across 32 lanes ---
    float push = 0.0f;
    for (int p = lane; p < MM * MM; p += 32) {
        const int m1 = p / MM;
        const int m2 = p - m1 * MM;
        if (s_valid[b][m1] && s_valid[b][m2]) {
            const float d = s_mean[b][m1] - s_mean[b][m2];
            push += __expf(-d * d);
        }
    }
    #pragma unroll
    for (int off = 16; off >= 1; off >>= 1)
        push += __shfl_xor(push, off);

    // --- per-batch finalize on lane 0 of each group ---
    if (lane == 0) {
        int n = 0;
        #pragma unroll
        for (int m = 0; m < MM; ++m) n += s_valid[b][m];
        const float nf = (float)n;
        float push_loss = 0.0f;
        if (n > 1) {
            float denom = nf * (nf - 1.0f);
            if (denom < 1.0f) denom = 1.0f;
            push_loss = push / denom * 0.5f;
        }
        float pull_loss = 0.0f;
        if (n > 0) {
            float denom = nf > 1.0f ? nf : 1.0f;
            pull_loss = pull / denom;
        }
        s_res[b][0] = pull_loss;
        s_res[b][1] = push_loss;
    }
    __syncthreads();

    if (tid == 0) {
        float pull_total = 0.0f, push_total = 0.0f;
        #pragma unroll
        for (int bb = 0; bb < BB; ++bb) {
            pull_total += s_res[bb][0];
            push_total += s_res[bb][1];
        }
        out[0] = pull_total;   // reference: (pull.sum(), push.sum())
        out[1] = push_total;
    }
}

extern "C" void kernel_launch(void* const* d_in, const int* in_sizes, int n_in,
                              void* d_out, int out_size, void* d_ws, size_t ws_size,
                              hipStream_t stream) {
    const float* tags = (const float*)d_in[0];
    const int*   kp   = (const int*)d_in[1];
    float*       out  = (float*)d_out;
    ae_loss_kernel<<<dim3(1), dim3(256), 0, stream>>>(tags, kp, out);
}

// Round 3
// 11.251 us; speedup vs baseline: 1.4312x; 1.2637x over previous
//
#include <hip/hip_runtime.h>

#define KK 17
#define MM 30
#define BB 8
#define HWN 262144

// One block, 256 threads. Threads [32b, 32b+31] handle batch b.
// Lane (tid&31) < 30 owns person m = lane: 17 branch-free int2 kp loads,
// then 17 branch-free unconditional tag gathers (mask applied as f32 mul).
// mean/valid exchanged via __shfl(width=32) — no LDS, no barrier — since a
// 32-lane group is wave-internal. Single __syncthreads for the final
// cross-batch reduction. Deterministic, no atomics, d_out fully overwritten.
__global__ __launch_bounds__(256) void ae_loss_kernel(
    const float* __restrict__ tags,       // (B, K, HW) f32
    const int*   __restrict__ kp,         // (B, M, K, 2) i32: [idx, vis]
    float*       __restrict__ out)        // out[0]=pull_total, out[1]=push_total
{
    const int tid  = threadIdx.x;
    const int b    = tid >> 5;   // 0..7
    const int lane = tid & 31;   // 0..31

    __shared__ float s_res[BB][2];   // [pull_loss, push_loss] per batch

    float mean    = 0.0f;
    float pull_pp = 0.0f;
    int   valid   = 0;

    if (lane < MM) {
        const int m = lane;
        const int2* __restrict__ kp2 =
            (const int2*)(kp + (size_t)(b * MM + m) * KK * 2);

        int   idxv[KK];
        float msk[KK];
        int   cnt = 0;
        #pragma unroll
        for (int k = 0; k < KK; ++k) {
            const int2 p = kp2[k];          // 17 independent 8-B loads
            idxv[k] = p.x;
            const int v = (p.y > 0) ? 1 : 0;
            msk[k]  = (float)v;
            cnt    += v;
        }

        // Unconditional gathers (reference gathers regardless of vis).
        float g[KK];
        #pragma unroll
        for (int k = 0; k < KK; ++k)
            g[k] = tags[(size_t)(b * KK + k) * HWN + idxv[k]];

        float sum = 0.0f;
        #pragma unroll
        for (int k = 0; k < KK; ++k)
            sum += g[k] * msk[k];

        const float safe_cnt = (float)(cnt > 1 ? cnt : 1);
        mean = sum / safe_cnt;

        float pp = 0.0f;
        #pragma unroll
        for (int k = 0; k < KK; ++k) {
            const float d = g[k] - mean;
            pp += msk[k] * d * d;
        }
        pp /= safe_cnt;

        valid   = (cnt > 0) ? 1 : 0;
        pull_pp = valid ? pp : 0.0f;
    }

    const float validf = (float)valid;

    // n = number of valid persons in this 32-lane group, via wave ballot.
    const unsigned long long bal = __ballot(valid != 0);
    const int n = __popcll((bal >> ((tid & 32))) & 0xffffffffull);

    // --- pull: reduce across the 32-lane group ---
    float pull = pull_pp;
    #pragma unroll
    for (int off = 16; off >= 1; off >>= 1)
        pull += __shfl_xor(pull, off);

    // --- push: 900 pairs across 32 lanes, operands via width-32 shuffles ---
    float push = 0.0f;
    for (int p = lane; p < MM * MM; p += 32) {
        const int m1 = p / MM;
        const int m2 = p - m1 * MM;
        const float mu1 = __shfl(mean,   m1, 32);
        const float v1  = __shfl(validf, m1, 32);
        const float mu2 = __shfl(mean,   m2, 32);
        const float v2  = __shfl(validf, m2, 32);
        const float d = mu1 - mu2;
        push += v1 * v2 * __expf(-d * d);
    }
    #pragma unroll
    for (int off = 16; off >= 1; off >>= 1)
        push += __shfl_xor(push, off);

    // --- per-batch finalize on lane 0 of each group ---
    if (lane == 0) {
        const float nf = (float)n;
        float push_loss = 0.0f;
        if (n > 1) {
            float denom = nf * (nf - 1.0f);
            if (denom < 1.0f) denom = 1.0f;
            push_loss = push / denom * 0.5f;
        }
        float pull_loss = 0.0f;
        if (n > 0) {
            float denom = nf > 1.0f ? nf : 1.0f;
            pull_loss = pull / denom;
        }
        s_res[b][0] = pull_loss;
        s_res[b][1] = push_loss;
    }
    __syncthreads();

    if (tid < 2) {
        float total = 0.0f;
        #pragma unroll
        for (int bb = 0; bb < BB; ++bb)
            total += s_res[bb][tid];
        out[tid] = total;   // out[0]=pull.sum(), out[1]=push.sum()
    }
}

extern "C" void kernel_launch(void* const* d_in, const int* in_sizes, int n_in,
                              void* d_out, int out_size, void* d_ws, size_t ws_size,
                              hipStream_t stream) {
    const float* tags = (const float*)d_in[0];
    const int*   kp   = (const int*)d_in[1];
    float*       out  = (float*)d_out;
    ae_loss_kernel<<<dim3(1), dim3(256), 0, stream>>>(tags, kp, out);
}